// Round 3
// baseline (368.413 us; speedup 1.0000x reference)
//
#include <hip/hip_runtime.h>

#define N_RES 2048
#define BATCH 16
#define LMAX  13
#define NSLOT 14          // 13 atm slots + 1 amn slot
#define DV    64
#define WT_FLOATS (20 * NSLOT * LMAX * DV)   // 232,960 floats
#define WT_BYTES  (WT_FLOATS * 4)            // 931,840 B

__device__ __constant__ int RES_LEN_D[20] = {3,4,5,5,6,6,6,7,7,7,7,7,8,8,8,9,10,10,11,13};

// ---------------------------------------------------------------------------
// prep: (a) blocks 0..279 transpose W_atm/W_amn -> WT[t][s][l][v] (v fastest)
//       (b) block 280 computes starts[i] = prefix sum of residue lengths
// ---------------------------------------------------------------------------
__global__ __launch_bounds__(256)
void prep_kernel(const float* __restrict__ W_amn,
                 const float* __restrict__ W_atm,
                 const int*   __restrict__ seq,
                 float* __restrict__ WT,
                 int*   __restrict__ starts)
{
  const int blk = blockIdx.x;
  const int tid = threadIdx.x;

  if (blk < 20 * NSLOT) {
    const int t = blk / NSLOT;
    const int s = blk - t * NSLOT;
    const float* src = (s < LMAX)
        ? W_atm + ((size_t)t * LMAX + s) * (DV * LMAX)   // [v][l]
        : W_amn + (size_t)t * (DV * LMAX);               // [o][l]
    float* dst = WT + (size_t)blk * (LMAX * DV);         // [l][v]
    for (int g = tid; g < LMAX * DV; g += 256) {
      int l = g >> 6;
      int v = g & 63;
      dst[g] = src[v * LMAX + l];                        // coalesced write
    }
  } else {
    // ---- prefix-sum of lens over 2048 residues: thread j owns [8j, 8j+8) ----
    __shared__ int ssum[256];
    const int base = tid * 8;
    int le[8];
    int s = 0;
    #pragma unroll
    for (int k = 0; k < 8; ++k) { le[k] = RES_LEN_D[seq[base + k]]; s += le[k]; }
    ssum[tid] = s;
    __syncthreads();
    #pragma unroll
    for (int off = 1; off < 256; off <<= 1) {            // Hillis-Steele inclusive
      int v = (tid >= off) ? ssum[tid - off] : 0;
      __syncthreads();
      ssum[tid] += v;
      __syncthreads();
    }
    int run = ssum[tid] - s;                             // exclusive offset
    #pragma unroll
    for (int k = 0; k < 8; ++k) { starts[base + k] = run; run += le[k]; }
  }
}

// ---------------------------------------------------------------------------
// main: block = residue i; thread = (b = tid>>4, va = tid&15)
// W read directly from L2-resident WT (one dwordx4 per (m,l)); diffs in
// named float4 registers; only one barrier in the whole kernel.
// ---------------------------------------------------------------------------
__global__ __launch_bounds__(256, 4)
void posmix_kernel(const float* __restrict__ pos_atm,
                   const float* __restrict__ pos_amn,
                   const int*   __restrict__ seq,
                   const float* __restrict__ WT,
                   const int*   __restrict__ starts,
                   float* __restrict__ out_atm,
                   float* __restrict__ out_amn,
                   int atoms)
{
  const int i   = blockIdx.x;
  const int tid = threadIdx.x;
  const int t   = seq[i];
  const int L   = RES_LEN_D[t];
  const int start = starts[i];

  __shared__ __align__(16) float diff_lds[BATCH * 40];   // [b][l*3+d], zero-padded

  if (tid < BATCH * LMAX) {
    int b = tid / LMAX;
    int l = tid - b * LMAX;
    float dx = 0.f, dy = 0.f, dz = 0.f;
    if (l < L) {
      const float* pa = pos_atm + ((size_t)b * atoms + (size_t)(start + l)) * 3;
      const float* pm = pos_amn + ((size_t)b * N_RES + i) * 3;
      dx = pa[0] - pm[0];
      dy = pa[1] - pm[1];
      dz = pa[2] - pm[2];
    }
    float* dd = diff_lds + b * 40 + l * 3;
    dd[0] = dx; dd[1] = dy; dd[2] = dz;
  }
  if (tid < BATCH) diff_lds[tid * 40 + 39] = 0.f;        // pad element
  __syncthreads();

  const int b  = tid >> 4;
  const int va = tid & 15;

  // named registers — fully static component access, cannot go to scratch
  const float4* s4 = (const float4*)(diff_lds + b * 40);
  const float4 d0 = s4[0], d1 = s4[1], d2 = s4[2], d3 = s4[3], d4 = s4[4];
  const float4 d5 = s4[5], d6 = s4[6], d7 = s4[7], d8 = s4[8], d9 = s4[9];

  // WT rows in float4 units: [(t*14+s)*13 + l] * 16 + va
  const float4* wt4 = (const float4*)WT + (size_t)(t * NSLOT) * (LMAX * 16) + va;

  float* outb_atm = out_atm + ((size_t)b * atoms + (size_t)start) * 192 + va * 12;
  float* outb_amn = out_amn + ((size_t)b * N_RES + i) * 192 + va * 12;

  for (int m = 0; m <= L; ++m) {
    const int sl = (m < L) ? m : 13;                     // amn weights live in slot 13
    const float4* wr = wt4 + (size_t)sl * (LMAX * 16);

    float acc[12];
    #pragma unroll
    for (int j = 0; j < 12; ++j) acc[j] = 0.f;

    #define STEP(LI, DX_, DY_, DZ_) { float4 w = wr[(LI) * 16]; \
      acc[0]  += w.x * DX_; acc[1]  += w.x * DY_; acc[2]  += w.x * DZ_; \
      acc[3]  += w.y * DX_; acc[4]  += w.y * DY_; acc[5]  += w.y * DZ_; \
      acc[6]  += w.z * DX_; acc[7]  += w.z * DY_; acc[8]  += w.z * DZ_; \
      acc[9]  += w.w * DX_; acc[10] += w.w * DY_; acc[11] += w.w * DZ_; }

    STEP(0,  d0.x, d0.y, d0.z)
    STEP(1,  d0.w, d1.x, d1.y)
    STEP(2,  d1.z, d1.w, d2.x)
    STEP(3,  d2.y, d2.z, d2.w)
    STEP(4,  d3.x, d3.y, d3.z)
    STEP(5,  d3.w, d4.x, d4.y)
    STEP(6,  d4.z, d4.w, d5.x)
    STEP(7,  d5.y, d5.z, d5.w)
    STEP(8,  d6.x, d6.y, d6.z)
    STEP(9,  d6.w, d7.x, d7.y)
    STEP(10, d7.z, d7.w, d8.x)
    STEP(11, d8.y, d8.z, d8.w)
    STEP(12, d9.x, d9.y, d9.z)
    #undef STEP

    float* dst = (m < L) ? (outb_atm + (size_t)m * 192) : outb_amn;
    ((float4*)dst)[0] = make_float4(acc[0], acc[1],  acc[2],  acc[3]);
    ((float4*)dst)[1] = make_float4(acc[4], acc[5],  acc[6],  acc[7]);
    ((float4*)dst)[2] = make_float4(acc[8], acc[9],  acc[10], acc[11]);
  }
}

extern "C" void kernel_launch(void* const* d_in, const int* in_sizes, int n_in,
                              void* d_out, int out_size, void* d_ws, size_t ws_size,
                              hipStream_t stream) {
  const float* pos_atm = (const float*)d_in[0];
  const float* pos_amn = (const float*)d_in[1];
  const float* W_amn   = (const float*)d_in[2];
  const float* W_atm   = (const float*)d_in[3];
  const int*   seq     = (const int*)d_in[4];

  const int atoms = in_sizes[0] / (BATCH * 3);   // 15036
  float* out_atm = (float*)d_out;
  float* out_amn = out_atm + (size_t)BATCH * atoms * DV * 3;

  float* WT     = (float*)d_ws;
  int*   starts = (int*)((char*)d_ws + WT_BYTES);

  prep_kernel<<<20 * NSLOT + 1, 256, 0, stream>>>(W_amn, W_atm, seq, WT, starts);
  posmix_kernel<<<N_RES, 256, 0, stream>>>(pos_atm, pos_amn, seq, WT, starts,
                                           out_atm, out_amn, atoms);
}